// Round 5
// baseline (907.129 us; speedup 1.0000x reference)
//
#include <hip/hip_runtime.h>
#include <math.h>

#define NN 50000
#define EE 800000
#define NEG 0.2f

using f32x4  = __attribute__((ext_vector_type(4))) float;
using bf16x8 = __attribute__((ext_vector_type(8))) short;

__device__ __forceinline__ float lrelu(float x){ return x > 0.f ? x : NEG*x; }

__device__ __forceinline__ unsigned short f2b(float f){
    unsigned int u = __float_as_uint(f);
    return (unsigned short)((u + 0x7FFFu + ((u >> 16) & 1u)) >> 16);  // RNE
}
__device__ __forceinline__ float b2f(unsigned short h){
    return __uint_as_float(((unsigned int)h) << 16);
}

// ---------------------------------------------------------------------------
// Weight packers (fragment-order bf16).
// Fusion: [kc][chunk=r*4+ct][lane][8]; only k < K-1 (ones-row via acc init).
//   element: r=chunk>>2, c=(chunk&3)*16+(l&15), k=kc*32+(l>>4)*8+j
// ---------------------------------------------------------------------------
__global__ void pack_w_fusion(const float* __restrict__ W, unsigned short* __restrict__ out,
                              int K, int NKC)
{
    int u = blockIdx.x * blockDim.x + threadIdx.x;
    if (u >= NKC * 16 * 64) return;
    int l = u & 63, chunk = (u >> 6) & 15, kc = u >> 10;
    int r = chunk >> 2, c = (chunk & 3) * 16 + (l & 15);
    int kb = kc * 32 + (l >> 4) * 8;
    bf16x8 v;
#pragma unroll
    for (int j = 0; j < 8; ++j)
        v[j] = (short)f2b(W[((size_t)r * K + kb + j) * 64 + c]);
    *(bf16x8*)(out + (size_t)u * 8) = v;
}

// GEMM weights: [kc][ct(C/16)][lane][8]; K multiple of 32.
__global__ void pack_w_gemm(const float* __restrict__ W, unsigned short* __restrict__ out,
                            int K, int C)
{
    int NCH = C / 16;
    int total = (K / 32) * NCH * 64;
    int u = blockIdx.x * blockDim.x + threadIdx.x;
    if (u >= total) return;
    int l = u & 63, ch = (u >> 6) % NCH, kc = u / (64 * NCH);
    int c = ch * 16 + (l & 15);
    int kb = kc * 32 + (l >> 4) * 8;
    bf16x8 v;
#pragma unroll
    for (int j = 0; j < 8; ++j)
        v[j] = (short)f2b(W[(size_t)(kb + j) * C + c]);
    *(bf16x8*)(out + (size_t)u * 8) = v;
}

// ---------------------------------------------------------------------------
// Fusion: barrier-free, LDS-free. One wave = 16 nodes x 32 cols, all 4 ranks.
// A-frag loaded straight from F rows (8 scalar f32 -> bf16); B-frag loaded
// straight from packed wp (1 dwordx4/lane, L1/L2-resident).
// acc initialized from the ones-column row W[r][K-1][c] (exact f32).
// ---------------------------------------------------------------------------
template<int K, int NKC>
__device__ __forceinline__ void fusion_pass_reg(
    const float* __restrict__ F, const unsigned short* __restrict__ wp,
    const float* __restrict__ W, int nb, int cb, int l, f32x4 (&acc)[4][2])
{
    const int c0 = cb + (l & 15);
#pragma unroll
    for (int r = 0; r < 4; ++r)
#pragma unroll
        for (int ct = 0; ct < 2; ++ct) {
            float wi = W[((size_t)r * K + (K - 1)) * 64 + c0 + ct * 16];
            acc[r][ct] = f32x4{wi, wi, wi, wi};
        }

    const float* fbase = F + (size_t)(nb + (l & 15)) * K + (l >> 4) * 8;
    const int chb = cb >> 4;   // 0 or 2
#pragma unroll
    for (int kc = 0; kc < NKC; ++kc) {
        bf16x8 af;
#pragma unroll
        for (int j = 0; j < 8; ++j) af[j] = (short)f2b(fbase[kc * 32 + j]);
        const unsigned short* wk = wp + (size_t)kc * 8192 + l * 8;
#pragma unroll
        for (int r = 0; r < 4; ++r)
#pragma unroll
            for (int ct = 0; ct < 2; ++ct) {
                bf16x8 bf = *(const bf16x8*)(wk + (r * 4 + chb + ct) * 512);
                acc[r][ct] = __builtin_amdgcn_mfma_f32_16x16x32_bf16(af, bf, acc[r][ct], 0, 0, 0);
            }
    }
}

__global__ __launch_bounds__(256) void fusion_mfma(
    const float* __restrict__ hc, const float* __restrict__ ht, const float* __restrict__ hr,
    const unsigned short* __restrict__ wpc, const unsigned short* __restrict__ wpt,
    const unsigned short* __restrict__ wpr,
    const float* __restrict__ Wc, const float* __restrict__ Wt, const float* __restrict__ Wr,
    const float* __restrict__ fw, const float* __restrict__ fb,
    unsigned short* __restrict__ h0b)
{
    const int wid = blockIdx.x * 4 + (threadIdx.x >> 6);
    const int tile = wid >> 1, half = wid & 1;
    if (tile >= NN / 16) return;
    const int l = threadIdx.x & 63;
    const int nb = tile * 16, cb = half * 32;

    f32x4 prod[4][2], acc[4][2];
    fusion_pass_reg<129, 4>(hc, wpc, Wc, nb, cb, l, acc);
#pragma unroll
    for (int r = 0; r < 4; ++r)
#pragma unroll
        for (int ct = 0; ct < 2; ++ct) prod[r][ct] = acc[r][ct];
    fusion_pass_reg<513, 16>(ht, wpt, Wt, nb, cb, l, acc);
#pragma unroll
    for (int r = 0; r < 4; ++r)
#pragma unroll
        for (int ct = 0; ct < 2; ++ct) prod[r][ct] *= acc[r][ct];
    fusion_pass_reg<513, 16>(hr, wpr, Wr, nb, cb, l, acc);
#pragma unroll
    for (int r = 0; r < 4; ++r)
#pragma unroll
        for (int ct = 0; ct < 2; ++ct) prod[r][ct] *= acc[r][ct];

    const float fw0 = fw[0], fw1 = fw[1], fw2 = fw[2], fw3 = fw[3];
#pragma unroll
    for (int ct = 0; ct < 2; ++ct) {
        int c = cb + ct * 16 + (l & 15);
        float fbc = fb[c];
#pragma unroll
        for (int q = 0; q < 4; ++q) {
            int n = nb + (l >> 4) * 4 + q;
            float v = fbc + fw0 * prod[0][ct][q] + fw1 * prod[1][ct][q]
                          + fw2 * prod[2][ct][q] + fw3 * prod[3][ct][q];
            v = v > 0.f ? v : expm1f(v);
            h0b[(size_t)n * 64 + c] = f2b(v);
        }
    }
}

// ---------------------------------------------------------------------------
// feat GEMM: barrier-free, LDS-free. Block = 16 nodes x 256 cols; wave w owns
// cols [64w, 64w+64). A rows are 16B-aligned bf16 -> single dwordx4 A-frag.
// ---------------------------------------------------------------------------
template<int K>
__global__ __launch_bounds__(256) void gemm_mfma(
    const unsigned short* __restrict__ Ab, const unsigned short* __restrict__ wp,
    unsigned short* __restrict__ featb)
{
    constexpr int NKC = K / 32;
    const int w = threadIdx.x >> 6, l = threadIdx.x & 63;
    const int nb = blockIdx.x * 16;

    f32x4 acc[4];
#pragma unroll
    for (int i = 0; i < 4; ++i) acc[i] = f32x4{0.f, 0.f, 0.f, 0.f};

    const unsigned short* abase = Ab + (size_t)(nb + (l & 15)) * K + (l >> 4) * 8;
#pragma unroll
    for (int kc = 0; kc < NKC; ++kc) {
        bf16x8 af = *(const bf16x8*)(abase + kc * 32);
        const unsigned short* wk = wp + (size_t)kc * 8192 + l * 8;
#pragma unroll
        for (int i = 0; i < 4; ++i) {
            bf16x8 bf = *(const bf16x8*)(wk + (w * 4 + i) * 512);
            acc[i] = __builtin_amdgcn_mfma_f32_16x16x32_bf16(af, bf, acc[i], 0, 0, 0);
        }
    }
#pragma unroll
    for (int i = 0; i < 4; ++i) {
        int c = (w * 4 + i) * 16 + (l & 15);
#pragma unroll
        for (int q = 0; q < 4; ++q) {
            int n = nb + (l >> 4) * 4 + q;
            featb[(size_t)n * 256 + c] = f2b(acc[i][q]);
        }
    }
}

// ---------------------------------------------------------------------------
// el/er: one wave per node, bf16 feat input.
// ---------------------------------------------------------------------------
__global__ __launch_bounds__(256) void elr_kernel(
    const unsigned short* __restrict__ featb,
    const float* __restrict__ al, const float* __restrict__ ar,
    float* __restrict__ el, float* __restrict__ er)
{
    int wid = (int)((blockIdx.x * (size_t)blockDim.x + threadIdx.x) >> 6);
    int lane = threadIdx.x & 63;
    if (wid >= NN) return;
    float elh[4], erh[4];
#pragma unroll
    for (int h = 0; h < 4; ++h) {
        float x = b2f(featb[(size_t)wid * 256 + h * 64 + lane]);
        elh[h] = x * al[h * 64 + lane];
        erh[h] = x * ar[h * 64 + lane];
    }
#pragma unroll
    for (int off = 32; off; off >>= 1) {
#pragma unroll
        for (int h = 0; h < 4; ++h) {
            elh[h] += __shfl_xor(elh[h], off);
            erh[h] += __shfl_xor(erh[h], off);
        }
    }
    if (lane == 0) {
        *(float4*)(el + (size_t)wid * 4) = make_float4(elh[0], elh[1], elh[2], elh[3]);
        *(float4*)(er + (size_t)wid * 4) = make_float4(erh[0], erh[1], erh[2], erh[3]);
    }
}

// ---------------------------------------------------------------------------
// CSR build
// ---------------------------------------------------------------------------
__global__ void hist_kernel(const int* __restrict__ dst, int* __restrict__ cnt)
{
    int e = blockIdx.x * blockDim.x + threadIdx.x;
    if (e < EE) atomicAdd(&cnt[dst[e]], 1);
}

__global__ __launch_bounds__(1024) void scan_kernel(const int* __restrict__ cnt, int* __restrict__ offs)
{
    __shared__ int tmp[1024];
    const int t = threadIdx.x;
    const int C = (NN + 1023) / 1024;
    int lo = t * C, hi = min(lo + C, NN);
    int s = 0;
    for (int i = lo; i < hi; ++i) s += cnt[i];
    tmp[t] = s;
    __syncthreads();
    for (int off = 1; off < 1024; off <<= 1) {
        int v = (t >= off) ? tmp[t - off] : 0;
        __syncthreads();
        tmp[t] += v;
        __syncthreads();
    }
    int run = (t == 0) ? 0 : tmp[t - 1];
    for (int i = lo; i < hi; ++i) { offs[i] = run; run += cnt[i]; }
    if (t == 1023) offs[NN] = tmp[1023];
}

__global__ void scatter_kernel(const int* __restrict__ dst, const int* __restrict__ offs,
                               int* __restrict__ cur, int* __restrict__ esort)
{
    int e = blockIdx.x * blockDim.x + threadIdx.x;
    if (e < EE) {
        int d = dst[e];
        int p = offs[d] + atomicAdd(&cur[d], 1);
        esort[p] = e;
    }
}

// ---------------------------------------------------------------------------
// edge_prep: CSR-ordered logits eesort[p] = lrelu(el[src[e]] + er[dst[e]]).
// ---------------------------------------------------------------------------
__global__ void edge_prep(const int* __restrict__ esort, const int* __restrict__ src,
                          const int* __restrict__ dst,
                          const float* __restrict__ el, const float* __restrict__ er,
                          float4* __restrict__ eesort)
{
    int p = blockIdx.x * blockDim.x + threadIdx.x;
    if (p >= EE) return;
    int e = esort[p];
    int s = src[e], d = dst[e];
    float4 l4 = *(const float4*)(el + (size_t)s * 4);
    float4 r4 = *(const float4*)(er + (size_t)d * 4);
    eesort[p] = make_float4(lrelu(l4.x + r4.x), lrelu(l4.y + r4.y),
                            lrelu(l4.z + r4.z), lrelu(l4.w + r4.w));
}

// ---------------------------------------------------------------------------
// Per-dst softmax + aggregation, coalesced logit stream. One wave per node.
// WMZ: store per-node (max, 1/z) for att_final. WB16: also store bf16 out.
// ---------------------------------------------------------------------------
template <int RESID, int WMZ, int WB16>
__global__ __launch_bounds__(256) void gat_agg(
    const int* __restrict__ esort, const int* __restrict__ src, const int* __restrict__ offs,
    const unsigned short* __restrict__ featb, const float4* __restrict__ eesort,
    const float* __restrict__ resid, const float* __restrict__ bias,
    float* __restrict__ out, unsigned short* __restrict__ outb,
    float4* __restrict__ mbuf, float4* __restrict__ zbuf)
{
    int n = (int)((blockIdx.x * (size_t)blockDim.x + threadIdx.x) >> 6);
    int lane = threadIdx.x & 63;
    if (n >= NN) return;
    int s0 = offs[n], s1 = offs[n + 1];

    float m0 = -1e30f, m1 = -1e30f, m2 = -1e30f, m3 = -1e30f;
    for (int p = s0 + lane; p < s1; p += 64) {
        float4 v = eesort[p];
        m0 = fmaxf(m0, v.x); m1 = fmaxf(m1, v.y);
        m2 = fmaxf(m2, v.z); m3 = fmaxf(m3, v.w);
    }
#pragma unroll
    for (int off = 32; off; off >>= 1) {
        m0 = fmaxf(m0, __shfl_xor(m0, off));
        m1 = fmaxf(m1, __shfl_xor(m1, off));
        m2 = fmaxf(m2, __shfl_xor(m2, off));
        m3 = fmaxf(m3, __shfl_xor(m3, off));
    }

    float z0 = 0.f, z1 = 0.f, z2 = 0.f, z3 = 0.f;
    for (int p = s0 + lane; p < s1; p += 64) {
        float4 v = eesort[p];
        z0 += expf(v.x - m0); z1 += expf(v.y - m1);
        z2 += expf(v.z - m2); z3 += expf(v.w - m3);
    }
#pragma unroll
    for (int off = 32; off; off >>= 1) {
        z0 += __shfl_xor(z0, off);
        z1 += __shfl_xor(z1, off);
        z2 += __shfl_xor(z2, off);
        z3 += __shfl_xor(z3, off);
    }
    float i0 = z0 > 0.f ? 1.f / z0 : 0.f;
    float i1 = z1 > 0.f ? 1.f / z1 : 0.f;
    float i2 = z2 > 0.f ? 1.f / z2 : 0.f;
    float i3 = z3 > 0.f ? 1.f / z3 : 0.f;
    if (WMZ && lane == 0) {
        mbuf[n] = make_float4(m0, m1, m2, m3);
        zbuf[n] = make_float4(i0, i1, i2, i3);
    }

    float a0 = 0.f, a1 = 0.f, a2 = 0.f, a3 = 0.f;
    for (int p = s0; p < s1; ++p) {
        float4 v = eesort[p];
        int s = src[esort[p]];
        float w0 = expf(v.x - m0) * i0;
        float w1 = expf(v.y - m1) * i1;
        float w2 = expf(v.z - m2) * i2;
        float w3 = expf(v.w - m3) * i3;
        const unsigned short* fp = featb + (size_t)s * 256;
        a0 += w0 * b2f(fp[lane]);
        a1 += w1 * b2f(fp[64 + lane]);
        a2 += w2 * b2f(fp[128 + lane]);
        a3 += w3 * b2f(fp[192 + lane]);
    }
    float o0 = a0 + bias[lane];
    float o1 = a1 + bias[64 + lane];
    float o2 = a2 + bias[128 + lane];
    float o3 = a3 + bias[192 + lane];
    if (RESID) {
        const float* rp = resid + (size_t)n * 256;
        o0 += rp[lane];
        o1 += rp[64 + lane];
        o2 += rp[128 + lane];
        o3 += rp[192 + lane];
    }
    float* op = out + (size_t)n * 256;
    op[lane] = o0;
    op[64 + lane] = o1;
    op[128 + lane] = o2;
    op[192 + lane] = o3;
    if (WB16) {
        unsigned short* ob = outb + (size_t)n * 256;
        ob[lane] = f2b(o0);
        ob[64 + lane] = f2b(o1);
        ob[128 + lane] = f2b(o2);
        ob[192 + lane] = f2b(o3);
    }
}

// ---------------------------------------------------------------------------
// att_final: att[e] = exp(lrelu(el[src]+er[dst]) - m[dst]) / z[dst]
// ---------------------------------------------------------------------------
__global__ void att_final(const int* __restrict__ src, const int* __restrict__ dst,
                          const float* __restrict__ el, const float* __restrict__ er,
                          const float4* __restrict__ mbuf, const float4* __restrict__ zbuf,
                          float4* __restrict__ att)
{
    int e = blockIdx.x * blockDim.x + threadIdx.x;
    if (e >= EE) return;
    int s = src[e], d = dst[e];
    float4 l4 = *(const float4*)(el + (size_t)s * 4);
    float4 r4 = *(const float4*)(er + (size_t)d * 4);
    float4 m4 = mbuf[d], zi = zbuf[d];
    att[e] = make_float4(expf(lrelu(l4.x + r4.x) - m4.x) * zi.x,
                         expf(lrelu(l4.y + r4.y) - m4.y) * zi.y,
                         expf(lrelu(l4.z + r4.z) - m4.z) * zi.z,
                         expf(lrelu(l4.w + r4.w) - m4.w) * zi.w);
}

// ---------------------------------------------------------------------------
extern "C" void kernel_launch(void* const* d_in, const int* in_sizes, int n_in,
                              void* d_out, int out_size, void* d_ws, size_t ws_size,
                              hipStream_t stream)
{
    const int*   src = (const int*)d_in[0];
    const int*   dst = (const int*)d_in[1];
    const float* hc  = (const float*)d_in[2];
    const float* ht  = (const float*)d_in[3];
    const float* hr  = (const float*)d_in[4];
    const float* Wc  = (const float*)d_in[5];
    const float* Wt  = (const float*)d_in[6];
    const float* Wr  = (const float*)d_in[7];
    const float* fw  = (const float*)d_in[8];
    const float* fb  = (const float*)d_in[9];
    const float* W0  = (const float*)d_in[10];
    const float* al0 = (const float*)d_in[11];
    const float* ar0 = (const float*)d_in[12];
    const float* b0  = (const float*)d_in[13];
    const float* W1  = (const float*)d_in[14];
    const float* al1 = (const float*)d_in[15];
    const float* ar1 = (const float*)d_in[16];
    const float* b1  = (const float*)d_in[17];

    // workspace layout (bytes)
    char* ws = (char*)d_ws;
    unsigned short* h0b   = (unsigned short*)(ws);               // N*64  bf16 :  6,400,000
    unsigned short* h1b   = (unsigned short*)(ws + 6400000);     // N*256 bf16 : 25,600,000
    unsigned short* featb = (unsigned short*)(ws + 32000000);    // N*256 bf16 : 25,600,000
    float* el    = (float*)(ws + 57600000);                      //    800,000
    float* er    = (float*)(ws + 58400000);                      //    800,000
    int*   cnt   = (int*)  (ws + 59200000);                      //    200,000
    int*   offs  = (int*)  (ws + 59400000);                      //    200,064 (padded)
    int*   esort = (int*)  (ws + 59600128);                      //  3,200,000
    unsigned short* wpc = (unsigned short*)(ws + 62800128);      //  4*16KB =  65,536
    unsigned short* wpt = (unsigned short*)(ws + 62865664);      // 16*16KB = 262,144
    unsigned short* wpr = (unsigned short*)(ws + 63127808);      // 16*16KB = 262,144
    unsigned short* wp0 = (unsigned short*)(ws + 63389952);      //  2*16KB =  32,768
    unsigned short* wp1 = (unsigned short*)(ws + 63422720);      //  8*16KB = 131,072
    float4* mbuf = (float4*)(ws + 63553792);                     //    800,000
    float4* zbuf = (float4*)(ws + 64353792);                     //    800,000
    if (ws_size < 65153792ull) return;                           // end of layout

    float* outh = (float*)d_out;                       // N*256 final h
    float4* atto = (float4*)(outh + (size_t)NN * 256); // E*4: eesort scratch, then final att

    // weight packing (fragment-order bf16; fusion packs exclude the ones-row)
    pack_w_fusion<<<(4 * 16 * 64 + 255) / 256, 256, 0, stream>>>(Wc, wpc, 129, 4);
    pack_w_fusion<<<(16 * 16 * 64 + 255) / 256, 256, 0, stream>>>(Wt, wpt, 513, 16);
    pack_w_fusion<<<(16 * 16 * 64 + 255) / 256, 256, 0, stream>>>(Wr, wpr, 513, 16);
    pack_w_gemm<<<(2 * 16 * 64 + 255) / 256, 256, 0, stream>>>(W0, wp0, 64, 256);
    pack_w_gemm<<<(8 * 16 * 64 + 255) / 256, 256, 0, stream>>>(W1, wp1, 256, 256);

    // Stage A: trilinear fusion (MFMA, barrier-free register pipeline)
    fusion_mfma<<<(NN / 16 * 2 + 3) / 4, 256, 0, stream>>>(hc, ht, hr, wpc, wpt, wpr,
                                                           Wc, Wt, Wr, fw, fb, h0b);

    // CSR by dst
    hipMemsetAsync(cnt, 0, NN * sizeof(int), stream);
    hist_kernel<<<(EE + 255) / 256, 256, 0, stream>>>(dst, cnt);
    scan_kernel<<<1, 1024, 0, stream>>>(cnt, offs);
    hipMemsetAsync(cnt, 0, NN * sizeof(int), stream);
    scatter_kernel<<<(EE + 255) / 256, 256, 0, stream>>>(dst, offs, cnt, esort);

    // GAT layer 0
    gemm_mfma<64><<<NN / 16, 256, 0, stream>>>(h0b, wp0, featb);
    elr_kernel<<<(NN * 64 + 255) / 256, 256, 0, stream>>>(featb, al0, ar0, el, er);
    edge_prep<<<(EE + 255) / 256, 256, 0, stream>>>(esort, src, dst, el, er, atto);
    gat_agg<0, 0, 1><<<(NN * 64 + 255) / 256, 256, 0, stream>>>(
        esort, src, offs, featb, atto, nullptr, b0, outh, h1b, nullptr, nullptr);

    // GAT layer 1
    gemm_mfma<256><<<NN / 16, 256, 0, stream>>>(h1b, wp1, featb);
    elr_kernel<<<(NN * 64 + 255) / 256, 256, 0, stream>>>(featb, al1, ar1, el, er);
    edge_prep<<<(EE + 255) / 256, 256, 0, stream>>>(esort, src, dst, el, er, atto);
    gat_agg<1, 1, 0><<<(NN * 64 + 255) / 256, 256, 0, stream>>>(
        esort, src, offs, featb, atto, outh, b1, outh, nullptr, mbuf, zbuf);
    att_final<<<(EE + 255) / 256, 256, 0, stream>>>(src, dst, el, er, mbuf, zbuf, atto);
}

// Round 6
// 772.692 us; speedup vs baseline: 1.1740x; 1.1740x over previous
//
#include <hip/hip_runtime.h>
#include <math.h>

#define NN 50000
#define EE 800000
#define NEG 0.2f

using f32x4  = __attribute__((ext_vector_type(4))) float;
using bf16x8 = __attribute__((ext_vector_type(8))) short;

__device__ __forceinline__ float lrelu(float x){ return x > 0.f ? x : NEG*x; }

__device__ __forceinline__ unsigned short f2b(float f){
    unsigned int u = __float_as_uint(f);
    return (unsigned short)((u + 0x7FFFu + ((u >> 16) & 1u)) >> 16);  // RNE
}
__device__ __forceinline__ float b2f(unsigned short h){
    return __uint_as_float(((unsigned int)h) << 16);
}
__device__ __forceinline__ void gld_lds16(const void* g, void* l){
    __builtin_amdgcn_global_load_lds(
        (const __attribute__((address_space(1))) unsigned int*)g,
        (__attribute__((address_space(3))) unsigned int*)l, 16, 0, 0);
}
__device__ __forceinline__ void gld_lds4(const void* g, void* l){
    __builtin_amdgcn_global_load_lds(
        (const __attribute__((address_space(1))) unsigned int*)g,
        (__attribute__((address_space(3))) unsigned int*)l, 4, 0, 0);
}

// ---------------------------------------------------------------------------
// Weight packers (fragment-order bf16).
// Fusion: chunk = ct*4 + r  (wave w owns ct=w, frag i=r). k < K-1 only.
// ---------------------------------------------------------------------------
__global__ void pack_w_fusion(const float* __restrict__ W, unsigned short* __restrict__ out,
                              int K, int NKC)
{
    int u = blockIdx.x * blockDim.x + threadIdx.x;
    if (u >= NKC * 16 * 64) return;
    int l = u & 63, chunk = (u >> 6) & 15, kc = u >> 10;
    int ct = chunk >> 2, r = chunk & 3;
    int c = ct * 16 + (l & 15);
    int kb = kc * 32 + (l >> 4) * 8;
    bf16x8 v;
#pragma unroll
    for (int j = 0; j < 8; ++j)
        v[j] = (short)f2b(W[((size_t)r * K + kb + j) * 64 + c]);
    *(bf16x8*)(out + (size_t)u * 8) = v;
}

// GEMM weights: chunk = ct (C/16 chunks); K multiple of 32.
__global__ void pack_w_gemm(const float* __restrict__ W, unsigned short* __restrict__ out,
                            int K, int C)
{
    int NCH = C / 16;
    int total = (K / 32) * NCH * 64;
    int u = blockIdx.x * blockDim.x + threadIdx.x;
    if (u >= total) return;
    int l = u & 63, ch = (u >> 6) % NCH, kc = u / (64 * NCH);
    int c = ch * 16 + (l & 15);
    int kb = kc * 32 + (l >> 4) * 8;
    bf16x8 v;
#pragma unroll
    for (int j = 0; j < 8; ++j)
        v[j] = (short)f2b(W[(size_t)(kb + j) * C + c]);
    *(bf16x8*)(out + (size_t)u * 8) = v;
}

// ---------------------------------------------------------------------------
// Shared GEMM pass: 64-node x 64-chunk-K tile, 4 waves, double-buffered LDS,
// single barrier per K-chunk, all staging via global_load_lds (coalesced).
// AF32: A staged as f32 rows (any 4B alignment), converted to bf16 in regs,
//       LDS layout [row][128B] with 16B-slot XOR swizzle s^=(row&7).
// bf16: A staged via gld_lds16, LDS [row][64B], slot swizzle s^=((row>>1)&3).
// B: packed fragment-order, wave w stages/reads global chunks {4w..4w+3}.
// ---------------------------------------------------------------------------
template<bool AF32, int KT, int NKC>
__device__ __forceinline__ void mm_pass(
    const void* __restrict__ Aptr, const unsigned short* __restrict__ wp,
    int nb, int w, int l, void* ldsAv, unsigned short* ldsB,
    f32x4 (&acc)[4][4])
{
    const int ABUF = AF32 ? 4096 : 2048;   // shorts per A buffer
    // prologue: stage chunk 0 -> buffer 0
    {
        if (AF32) {
            const float* F = (const float*)Aptr;
#pragma unroll
            for (int j = 0; j < 8; ++j) {
                int u = (w * 8 + j) * 64 + l;
                int row = u >> 5, dsw = u & 31;
                int s = (dsw >> 2) ^ (row & 7), o = dsw & 3;
                int n = nb + row; if (n >= NN) n = NN - 1;
                gld_lds4(F + (size_t)n * KT + s * 4 + o,
                         (char*)ldsAv + (w * 8 + j) * 256);
            }
        } else {
            const unsigned short* F = (const unsigned short*)Aptr;
            int u = w * 64 + l;
            int row = u >> 2, sl = u & 3;
            int s = sl ^ ((row >> 1) & 3);
            int n = nb + row; if (n >= NN) n = NN - 1;
            gld_lds16(F + (size_t)n * KT + s * 8,
                      (unsigned short*)ldsAv + w * 512);
        }
#pragma unroll
        for (int i = 0; i < 4; ++i)
            gld_lds16(wp + (size_t)(w * 4 + i) * 512 + l * 8, ldsB + (w * 4 + i) * 512);
    }
    __syncthreads();

    for (int t = 0; t < NKC; ++t) {
        const int cur = t & 1;
        // stage chunk t+1 into the other buffer (in flight during compute)
        if (t + 1 < NKC) {
            char* nA = (char*)ldsAv + (cur ^ 1) * (ABUF * 2);
            unsigned short* nB = ldsB + (cur ^ 1) * 8192;
            if (AF32) {
                const float* F = (const float*)Aptr;
#pragma unroll
                for (int j = 0; j < 8; ++j) {
                    int u = (w * 8 + j) * 64 + l;
                    int row = u >> 5, dsw = u & 31;
                    int s = (dsw >> 2) ^ (row & 7), o = dsw & 3;
                    int n = nb + row; if (n >= NN) n = NN - 1;
                    gld_lds4(F + (size_t)n * KT + (t + 1) * 32 + s * 4 + o,
                             nA + (w * 8 + j) * 256);
                }
            } else {
                const unsigned short* F = (const unsigned short*)Aptr;
                int u = w * 64 + l;
                int row = u >> 2, sl = u & 3;
                int s = sl ^ ((row >> 1) & 3);
                int n = nb + row; if (n >= NN) n = NN - 1;
                gld_lds16(F + (size_t)n * KT + (t + 1) * 32 + s * 8,
                          (unsigned short*)nA + w * 512);
            }
            const unsigned short* wsrc = wp + (size_t)(t + 1) * 8192;
#pragma unroll
            for (int i = 0; i < 4; ++i)
                gld_lds16(wsrc + (w * 4 + i) * 512 + l * 8, nB + (w * 4 + i) * 512);
        }
        // compute chunk t
        unsigned short* lB = ldsB + cur * 8192;
        bf16x8 bfr[4];
#pragma unroll
        for (int i = 0; i < 4; ++i)
            bfr[i] = *(const bf16x8*)(lB + ((w * 4 + i) * 64 + l) * 8);
#pragma unroll
        for (int nf = 0; nf < 4; ++nf) {
            int row = nf * 16 + (l & 15);
            bf16x8 af;
            if (AF32) {
                const float* fA = (const float*)((char*)ldsAv + cur * (ABUF * 2));
#pragma unroll
                for (int h = 0; h < 2; ++h) {
                    int so = ((l >> 4) * 2 + h) ^ (row & 7);
                    f32x4 v = *(const f32x4*)(fA + row * 32 + so * 4);
#pragma unroll
                    for (int o = 0; o < 4; ++o) af[h * 4 + o] = (short)f2b(v[o]);
                }
            } else {
                const unsigned short* sA = (const unsigned short*)ldsAv + cur * ABUF;
                int so = (l >> 4) ^ ((row >> 1) & 3);
                af = *(const bf16x8*)(sA + row * 32 + so * 8);
            }
#pragma unroll
            for (int i = 0; i < 4; ++i)
                acc[i][nf] = __builtin_amdgcn_mfma_f32_16x16x32_bf16(af, bfr[i], acc[i][nf], 0, 0, 0);
        }
        __syncthreads();
    }
}

// ---------------------------------------------------------------------------
// Fusion: 3 passes (hc K=129, ht/hr K=513), elementwise product over ranks,
// acc initialized from the ones-row W[r][K-1][c] (exact f32).
// Block = 64 nodes x 64 cols (wave w owns ct=w, frag i = rank r).
// ---------------------------------------------------------------------------
__global__ __launch_bounds__(256) void fusion_mfma(
    const float* __restrict__ hc, const float* __restrict__ ht, const float* __restrict__ hr,
    const unsigned short* __restrict__ wpc, const unsigned short* __restrict__ wpt,
    const unsigned short* __restrict__ wpr,
    const float* __restrict__ Wc, const float* __restrict__ Wt, const float* __restrict__ Wr,
    const float* __restrict__ fw, const float* __restrict__ fb,
    unsigned short* __restrict__ h0b)
{
    __shared__ float          ldsA[4096];    // 2 x 8KB (f32 A tiles)
    __shared__ unsigned short ldsB[16384];   // 2 x 16KB
    const int tid = threadIdx.x, w = tid >> 6, l = tid & 63;
    const int nb = blockIdx.x * 64;
    const int c = w * 16 + (l & 15);

    f32x4 prod[4][4], acc[4][4];

#pragma unroll
    for (int r = 0; r < 4; ++r) {
        float wi = Wc[((size_t)r * 129 + 128) * 64 + c];
#pragma unroll
        for (int nf = 0; nf < 4; ++nf) acc[r][nf] = f32x4{wi, wi, wi, wi};
    }
    mm_pass<true, 129, 4>(hc, wpc, nb, w, l, ldsA, ldsB, acc);
#pragma unroll
    for (int r = 0; r < 4; ++r)
#pragma unroll
        for (int nf = 0; nf < 4; ++nf) prod[r][nf] = acc[r][nf];

#pragma unroll
    for (int r = 0; r < 4; ++r) {
        float wi = Wt[((size_t)r * 513 + 512) * 64 + c];
#pragma unroll
        for (int nf = 0; nf < 4; ++nf) acc[r][nf] = f32x4{wi, wi, wi, wi};
    }
    mm_pass<true, 513, 16>(ht, wpt, nb, w, l, ldsA, ldsB, acc);
#pragma unroll
    for (int r = 0; r < 4; ++r)
#pragma unroll
        for (int nf = 0; nf < 4; ++nf) prod[r][nf] *= acc[r][nf];

#pragma unroll
    for (int r = 0; r < 4; ++r) {
        float wi = Wr[((size_t)r * 513 + 512) * 64 + c];
#pragma unroll
        for (int nf = 0; nf < 4; ++nf) acc[r][nf] = f32x4{wi, wi, wi, wi};
    }
    mm_pass<true, 513, 16>(hr, wpr, nb, w, l, ldsA, ldsB, acc);
#pragma unroll
    for (int r = 0; r < 4; ++r)
#pragma unroll
        for (int nf = 0; nf < 4; ++nf) prod[r][nf] *= acc[r][nf];

    const float fw0 = fw[0], fw1 = fw[1], fw2 = fw[2], fw3 = fw[3];
    const float fbc = fb[c];
#pragma unroll
    for (int nf = 0; nf < 4; ++nf)
#pragma unroll
        for (int q = 0; q < 4; ++q) {
            int n = nb + nf * 16 + (l >> 4) * 4 + q;
            if (n < NN) {
                float v = fbc + fw0 * prod[0][nf][q] + fw1 * prod[1][nf][q]
                              + fw2 * prod[2][nf][q] + fw3 * prod[3][nf][q];
                v = v > 0.f ? v : expm1f(v);
                h0b[(size_t)n * 64 + c] = f2b(v);
            }
        }
}

// ---------------------------------------------------------------------------
// feat GEMM: bf16 A rows (128B/512B aligned), C=256; wave w owns cts {4w..4w+3}.
// ---------------------------------------------------------------------------
template<int K>
__global__ __launch_bounds__(256) void gemm_mfma(
    const unsigned short* __restrict__ Ab, const unsigned short* __restrict__ wp,
    unsigned short* __restrict__ featb)
{
    __shared__ unsigned short ldsA[4096];    // 2 x 4KB
    __shared__ unsigned short ldsB[16384];   // 2 x 16KB
    const int tid = threadIdx.x, w = tid >> 6, l = tid & 63;
    const int nb = blockIdx.x * 64;

    f32x4 acc[4][4];
#pragma unroll
    for (int i = 0; i < 4; ++i)
#pragma unroll
        for (int nf = 0; nf < 4; ++nf) acc[i][nf] = f32x4{0.f, 0.f, 0.f, 0.f};

    mm_pass<false, K, K / 32>(Ab, wp, nb, w, l, ldsA, ldsB, acc);

#pragma unroll
    for (int i = 0; i < 4; ++i) {
        int c = (w * 4 + i) * 16 + (l & 15);
#pragma unroll
        for (int nf = 0; nf < 4; ++nf)
#pragma unroll
            for (int q = 0; q < 4; ++q) {
                int n = nb + nf * 16 + (l >> 4) * 4 + q;
                if (n < NN) featb[(size_t)n * 256 + c] = f2b(acc[i][nf][q]);
            }
    }
}

// ---------------------------------------------------------------------------
// el/er: one wave per node, bf16 feat input.
// ---------------------------------------------------------------------------
__global__ __launch_bounds__(256) void elr_kernel(
    const unsigned short* __restrict__ featb,
    const float* __restrict__ al, const float* __restrict__ ar,
    float* __restrict__ el, float* __restrict__ er)
{
    int wid = (int)((blockIdx.x * (size_t)blockDim.x + threadIdx.x) >> 6);
    int lane = threadIdx.x & 63;
    if (wid >= NN) return;
    float elh[4], erh[4];
#pragma unroll
    for (int h = 0; h < 4; ++h) {
        float x = b2f(featb[(size_t)wid * 256 + h * 64 + lane]);
        elh[h] = x * al[h * 64 + lane];
        erh[h] = x * ar[h * 64 + lane];
    }
#pragma unroll
    for (int off = 32; off; off >>= 1) {
#pragma unroll
        for (int h = 0; h < 4; ++h) {
            elh[h] += __shfl_xor(elh[h], off);
            erh[h] += __shfl_xor(erh[h], off);
        }
    }
    if (lane == 0) {
        *(float4*)(el + (size_t)wid * 4) = make_float4(elh[0], elh[1], elh[2], elh[3]);
        *(float4*)(er + (size_t)wid * 4) = make_float4(erh[0], erh[1], erh[2], erh[3]);
    }
}

// ---------------------------------------------------------------------------
// CSR build
// ---------------------------------------------------------------------------
__global__ void hist_kernel(const int* __restrict__ dst, int* __restrict__ cnt)
{
    int e = blockIdx.x * blockDim.x + threadIdx.x;
    if (e < EE) atomicAdd(&cnt[dst[e]], 1);
}

__global__ __launch_bounds__(1024) void scan_kernel(const int* __restrict__ cnt, int* __restrict__ offs)
{
    __shared__ int tmp[1024];
    const int t = threadIdx.x;
    const int C = (NN + 1023) / 1024;
    int lo = t * C, hi = min(lo + C, NN);
    int s = 0;
    for (int i = lo; i < hi; ++i) s += cnt[i];
    tmp[t] = s;
    __syncthreads();
    for (int off = 1; off < 1024; off <<= 1) {
        int v = (t >= off) ? tmp[t - off] : 0;
        __syncthreads();
        tmp[t] += v;
        __syncthreads();
    }
    int run = (t == 0) ? 0 : tmp[t - 1];
    for (int i = lo; i < hi; ++i) { offs[i] = run; run += cnt[i]; }
    if (t == 1023) offs[NN] = tmp[1023];
}

__global__ void scatter_kernel(const int* __restrict__ dst, const int* __restrict__ offs,
                               int* __restrict__ cur, int* __restrict__ esort)
{
    int e = blockIdx.x * blockDim.x + threadIdx.x;
    if (e < EE) {
        int d = dst[e];
        int p = offs[d] + atomicAdd(&cur[d], 1);
        esort[p] = e;
    }
}

// ---------------------------------------------------------------------------
// edge_prep: CSR-ordered logits eesort[p] = lrelu(el[src[e]] + er[dst[e]]).
// ---------------------------------------------------------------------------
__global__ void edge_prep(const int* __restrict__ esort, const int* __restrict__ src,
                          const int* __restrict__ dst,
                          const float* __restrict__ el, const float* __restrict__ er,
                          float4* __restrict__ eesort)
{
    int p = blockIdx.x * blockDim.x + threadIdx.x;
    if (p >= EE) return;
    int e = esort[p];
    int s = src[e], d = dst[e];
    float4 l4 = *(const float4*)(el + (size_t)s * 4);
    float4 r4 = *(const float4*)(er + (size_t)d * 4);
    eesort[p] = make_float4(lrelu(l4.x + r4.x), lrelu(l4.y + r4.y),
                            lrelu(l4.z + r4.z), lrelu(l4.w + r4.w));
}

// ---------------------------------------------------------------------------
// Per-dst softmax + aggregation, coalesced logit stream. One wave per node.
// Pass C unrolled x2 with dual accumulators (halve serial gather/add chain).
// ---------------------------------------------------------------------------
template <int RESID, int WMZ, int WB16>
__global__ __launch_bounds__(256) void gat_agg(
    const int* __restrict__ esort, const int* __restrict__ src, const int* __restrict__ offs,
    const unsigned short* __restrict__ featb, const float4* __restrict__ eesort,
    const float* __restrict__ resid, const float* __restrict__ bias,
    float* __restrict__ out, unsigned short* __restrict__ outb,
    float4* __restrict__ mbuf, float4* __restrict__ zbuf)
{
    int n = (int)((blockIdx.x * (size_t)blockDim.x + threadIdx.x) >> 6);
    int lane = threadIdx.x & 63;
    if (n >= NN) return;
    int s0 = offs[n], s1 = offs[n + 1];

    float m0 = -1e30f, m1 = -1e30f, m2 = -1e30f, m3 = -1e30f;
    for (int p = s0 + lane; p < s1; p += 64) {
        float4 v = eesort[p];
        m0 = fmaxf(m0, v.x); m1 = fmaxf(m1, v.y);
        m2 = fmaxf(m2, v.z); m3 = fmaxf(m3, v.w);
    }
#pragma unroll
    for (int off = 32; off; off >>= 1) {
        m0 = fmaxf(m0, __shfl_xor(m0, off));
        m1 = fmaxf(m1, __shfl_xor(m1, off));
        m2 = fmaxf(m2, __shfl_xor(m2, off));
        m3 = fmaxf(m3, __shfl_xor(m3, off));
    }

    float z0 = 0.f, z1 = 0.f, z2 = 0.f, z3 = 0.f;
    for (int p = s0 + lane; p < s1; p += 64) {
        float4 v = eesort[p];
        z0 += expf(v.x - m0); z1 += expf(v.y - m1);
        z2 += expf(v.z - m2); z3 += expf(v.w - m3);
    }
#pragma unroll
    for (int off = 32; off; off >>= 1) {
        z0 += __shfl_xor(z0, off);
        z1 += __shfl_xor(z1, off);
        z2 += __shfl_xor(z2, off);
        z3 += __shfl_xor(z3, off);
    }
    float i0 = z0 > 0.f ? 1.f / z0 : 0.f;
    float i1 = z1 > 0.f ? 1.f / z1 : 0.f;
    float i2 = z2 > 0.f ? 1.f / z2 : 0.f;
    float i3 = z3 > 0.f ? 1.f / z3 : 0.f;
    if (WMZ && lane == 0) {
        mbuf[n] = make_float4(m0, m1, m2, m3);
        zbuf[n] = make_float4(i0, i1, i2, i3);
    }

    float a0 = 0.f, a1 = 0.f, a2 = 0.f, a3 = 0.f;
    float c0 = 0.f, c1 = 0.f, c2 = 0.f, c3 = 0.f;
    int p = s0;
    for (; p + 1 < s1; p += 2) {
        float4 vA = eesort[p], vB = eesort[p + 1];
        int sA = src[esort[p]], sB = src[esort[p + 1]];
        const unsigned short* fA = featb + (size_t)sA * 256;
        const unsigned short* fB = featb + (size_t)sB * 256;
        float wA0 = expf(vA.x - m0) * i0, wB0 = expf(vB.x - m0) * i0;
        float wA1 = expf(vA.y - m1) * i1, wB1 = expf(vB.y - m1) * i1;
        float wA2 = expf(vA.z - m2) * i2, wB2 = expf(vB.z - m2) * i2;
        float wA3 = expf(vA.w - m3) * i3, wB3 = expf(vB.w - m3) * i3;
        a0 += wA0 * b2f(fA[lane]);        c0 += wB0 * b2f(fB[lane]);
        a1 += wA1 * b2f(fA[64 + lane]);   c1 += wB1 * b2f(fB[64 + lane]);
        a2 += wA2 * b2f(fA[128 + lane]);  c2 += wB2 * b2f(fB[128 + lane]);
        a3 += wA3 * b2f(fA[192 + lane]);  c3 += wB3 * b2f(fB[192 + lane]);
    }
    if (p < s1) {
        float4 v = eesort[p];
        int s = src[esort[p]];
        const unsigned short* fp = featb + (size_t)s * 256;
        a0 += expf(v.x - m0) * i0 * b2f(fp[lane]);
        a1 += expf(v.y - m1) * i1 * b2f(fp[64 + lane]);
        a2 += expf(v.z - m2) * i2 * b2f(fp[128 + lane]);
        a3 += expf(v.w - m3) * i3 * b2f(fp[192 + lane]);
    }
    a0 += c0; a1 += c1; a2 += c2; a3 += c3;

    float o0 = a0 + bias[lane];
    float o1 = a1 + bias[64 + lane];
    float o2 = a2 + bias[128 + lane];
    float o3 = a3 + bias[192 + lane];
    if (RESID) {
        const float* rp = resid + (size_t)n * 256;
        o0 += rp[lane];
        o1 += rp[64 + lane];
        o2 += rp[128 + lane];
        o3 += rp[192 + lane];
    }
    float* op = out + (size_t)n * 256;
    op[lane] = o0;
    op[64 + lane] = o1;
    op[128 + lane] = o2;
    op[192 + lane] = o3;
    if (WB16) {
        unsigned short* ob = outb + (size_t)n * 256;
        ob[lane] = f2b(o0);
        ob[64 + lane] = f2b(o1);
        ob[128 + lane] = f2b(o2);
        ob[192 + lane] = f2b(o3);
    }
}

// ---------------------------------------------------------------------------
// att_final: att[e] = exp(lrelu(el[src]+er[dst]) - m[dst]) / z[dst]
// ---------------------------------------------------------------------------
__global__ void att_final(const int* __restrict__ src, const int* __restrict__ dst,
                          const float* __restrict__ el, const float* __restrict__ er,
                          const float4* __restrict__ mbuf, const float4* __restrict__ zbuf,
                          float4* __restrict__ att)
{
    int e = blockIdx.x * blockDim.x + threadIdx.x;
    if (e >= EE) return;
    int s = src[e], d = dst[e];
    float4 l4 = *(const float4*)(el + (size_t)s * 4);
    float4 r4 = *(const float4*)(er + (size_t)d * 4);
    float4 m4 = mbuf[d], zi = zbuf[d];
    att[e] = make_float4(expf(lrelu(l4.x + r4.x) - m4.x) * zi.x,
                         expf(lrelu(l4.y + r4.y) - m4.y) * zi.y,
                         expf(lrelu(l4.z + r4.z) - m4.z) * zi.z,
                         expf(lrelu(l4.w + r4.w) - m4.w) * zi.w);
}

// ---------------------------------------------------------------------------
extern "C" void kernel_launch(void* const* d_in, const int* in_sizes, int n_in,
                              void* d_out, int out_size, void* d_ws, size_t ws_size,
                              hipStream_t stream)
{
    const int*   src = (const int*)d_in[0];
    const int*   dst = (const int*)d_in[1];
    const float* hc  = (const float*)d_in[2];
    const float* ht  = (const float*)d_in[3];
    const float* hr  = (const float*)d_in[4];
    const float* Wc  = (const float*)d_in[5];
    const float* Wt  = (const float*)d_in[6];
    const float* Wr  = (const float*)d_in[7];
    const float* fw  = (const float*)d_in[8];
    const float* fb  = (const float*)d_in[9];
    const float* W0  = (const float*)d_in[10];
    const float* al0 = (const float*)d_in[11];
    const float* ar0 = (const float*)d_in[12];
    const float* b0  = (const float*)d_in[13];
    const float* W1  = (const float*)d_in[14];
    const float* al1 = (const float*)d_in[15];
    const float* ar1 = (const float*)d_in[16];
    const float* b1  = (const float*)d_in[17];

    // workspace layout (bytes) — unchanged from round 5 (known-fit)
    char* ws = (char*)d_ws;
    unsigned short* h0b   = (unsigned short*)(ws);               // N*64  bf16 :  6,400,000
    unsigned short* h1b   = (unsigned short*)(ws + 6400000);     // N*256 bf16 : 25,600,000
    unsigned short* featb = (unsigned short*)(ws + 32000000);    // N*256 bf16 : 25,600,000
    float* el    = (float*)(ws + 57600000);                      //    800,000
    float* er    = (float*)(ws + 58400000);                      //    800,000
    int*   cnt   = (int*)  (ws + 59200000);                      //    200,000
    int*   offs  = (int*)  (ws + 59400000);                      //    200,064 (padded)
    int*   esort = (int*)  (ws + 59600128);                      //  3,200,000
    unsigned short* wpc = (unsigned short*)(ws + 62800128);      //  4*16KB =  65,536
    unsigned short* wpt = (unsigned short*)(ws + 62865664);      // 16*16KB = 262,144
    unsigned short* wpr = (unsigned short*)(ws + 63127808);      // 16*16KB = 262,144
    unsigned short* wp0 = (unsigned short*)(ws + 63389952);      //  2*16KB =  32,768
    unsigned short* wp1 = (unsigned short*)(ws + 63422720);      //  8*16KB = 131,072
    float4* mbuf = (float4*)(ws + 63553792);                     //    800,000
    float4* zbuf = (float4*)(ws + 64353792);                     //    800,000
    if (ws_size < 65153792ull) return;                           // end of layout

    float* outh = (float*)d_out;                       // N*256 final h
    float4* atto = (float4*)(outh + (size_t)NN * 256); // E*4: eesort scratch, then final att

    // weight packing (fragment-order bf16; fusion packs exclude the ones-row)
    pack_w_fusion<<<(4 * 16 * 64 + 255) / 256, 256, 0, stream>>>(Wc, wpc, 129, 4);
    pack_w_fusion<<<(16 * 16 * 64 + 255) / 256, 256, 0, stream>>>(Wt, wpt, 513, 16);
    pack_w_fusion<<<(16 * 16 * 64 + 255) / 256, 256, 0, stream>>>(Wr, wpr, 513, 16);
    pack_w_gemm<<<(2 * 16 * 64 + 255) / 256, 256, 0, stream>>>(W0, wp0, 64, 256);
    pack_w_gemm<<<(8 * 16 * 64 + 255) / 256, 256, 0, stream>>>(W1, wp1, 256, 256);

    // Stage A: trilinear fusion (MFMA, coalesced gld_lds staging, dbuf)
    fusion_mfma<<<(NN + 63) / 64, 256, 0, stream>>>(hc, ht, hr, wpc, wpt, wpr,
                                                    Wc, Wt, Wr, fw, fb, h0b);

    // CSR by dst
    hipMemsetAsync(cnt, 0, NN * sizeof(int), stream);
    hist_kernel<<<(EE + 255) / 256, 256, 0, stream>>>(dst, cnt);
    scan_kernel<<<1, 1024, 0, stream>>>(cnt, offs);
    hipMemsetAsync(cnt, 0, NN * sizeof(int), stream);
    scatter_kernel<<<(EE + 255) / 256, 256, 0, stream>>>(dst, offs, cnt, esort);

    // GAT layer 0
    gemm_mfma<64><<<(NN + 63) / 64, 256, 0, stream>>>(h0b, wp0, featb);
    elr_kernel<<<(NN * 64 + 255) / 256, 256, 0, stream>>>(featb, al0, ar0, el, er);
    edge_prep<<<(EE + 255) / 256, 256, 0, stream>>>(esort, src, dst, el, er, atto);
    gat_agg<0, 0, 1><<<(NN * 64 + 255) / 256, 256, 0, stream>>>(
        esort, src, offs, featb, atto, nullptr, b0, outh, h1b, nullptr, nullptr);

    // GAT layer 1
    gemm_mfma<256><<<(NN + 63) / 64, 256, 0, stream>>>(h1b, wp1, featb);
    elr_kernel<<<(NN * 64 + 255) / 256, 256, 0, stream>>>(featb, al1, ar1, el, er);
    edge_prep<<<(EE + 255) / 256, 256, 0, stream>>>(esort, src, dst, el, er, atto);
    gat_agg<1, 1, 0><<<(NN * 64 + 255) / 256, 256, 0, stream>>>(
        esort, src, offs, featb, atto, outh, b1, outh, nullptr, mbuf, zbuf);
    att_final<<<(EE + 255) / 256, 256, 0, stream>>>(src, dst, el, er, mbuf, zbuf, atto);
}